// Round 7
// baseline (166.308 us; speedup 1.0000x reference)
//
#include <hip/hip_runtime.h>

#define HIDDEN 256
#define GAMMA_F 12.0f
#define BATCH 8
#define ROWS_PER_GRP 4
#define GRP_FLOATS (ROWS_PER_GRP * HIDDEN)   // 1024 floats = 4 KB

// async global->LDS DMA, 16B per lane: lane l loads gsrc[l*4 .. l*4+4) floats
// into wave-uniform ldst + l*16B. One inst stages 1KB (one entity row).
__device__ __forceinline__ void dma_row_16(const float* gsrc, float* ldst) {
    __builtin_amdgcn_global_load_lds(
        (const __attribute__((address_space(1))) unsigned int*)gsrc,
        (__attribute__((address_space(3))) unsigned int*)ldst,
        16, 0, 0);
}

// s_waitcnt imm (gfx9): vmcnt[3:0] | expcnt<<4 | lgkmcnt<<8 | vmcnt[5:4]<<14
#define WAITCNT_VM4 0xF74   // vmcnt(4), lgkm/exp unconstrained
#define WAITCNT_VM0 0xF70   // vmcnt(0)

// ---------------------------------------------------------------------------
// Kernel A: stream the entity table once. Per-wave double-buffered LDS
// staging via global_load_lds: 4 rows (4KB) per group, 4 DMA insts per
// prefetch, s_waitcnt vmcnt(4) overlaps next-group DMA with current compute.
// Lane layout (r6): r=lane>>5 (row in pair), c=lane&31 (16B dim chunk).
// Per group: 2 pair-trees (9 swizzles each) -> 32 results, half-wave store.
// ---------------------------------------------------------------------------
__global__ __launch_bounds__(256, 4) void kge_dist_kernel(
    const float* __restrict__ ent,
    const float* __restrict__ rel,
    const int*  __restrict__ pos,
    float* __restrict__ dist,   // [nent, 8]
    int ngroups, int nent, int nwaves)
{
    __shared__ float lds[4][2][GRP_FLOATS];   // 4 waves x 2 bufs x 4KB = 32KB

    const int lane = threadIdx.x & 63;
    const int wslot = threadIdx.x >> 6;
    const int r_ = lane >> 5;
    const int c = lane & 31;
    const int wave_gid = (blockIdx.x * 256 + threadIdx.x) >> 6;

    // hr[b] = head_b + rel_b at this lane's 8 dims (64 VGPRs, loaded once)
    float4 hrA[BATCH], hrB[BATCH];
    #pragma unroll
    for (int b = 0; b < BATCH; ++b) {
        const int hidx = pos[b * 3 + 0];
        const int ridx = pos[b * 3 + 1];
        const float* hrow = ent + (size_t)hidx * HIDDEN;
        const float* rrow = rel + (size_t)ridx * HIDDEN;
        float4 h = *(const float4*)(hrow + c * 4);
        float4 q = *(const float4*)(rrow + c * 4);
        hrA[b] = make_float4(h.x + q.x, h.y + q.y, h.z + q.z, h.w + q.w);
        h = *(const float4*)(hrow + 128 + c * 4);
        q = *(const float4*)(rrow + 128 + c * 4);
        hrB[b] = make_float4(h.x + q.x, h.y + q.y, h.z + q.z, h.w + q.w);
    }

    // clean vmcnt state before manual DMA bookkeeping
    __builtin_amdgcn_s_waitcnt(WAITCNT_VM0);

    int g = wave_gid;
    int p = 0;
    if (g < ngroups) {
        const float* base = ent + (size_t)g * GRP_FLOATS;
        #pragma unroll
        for (int rr = 0; rr < ROWS_PER_GRP; ++rr)
            dma_row_16(base + rr * HIDDEN + lane * 4, &lds[wslot][0][rr * HIDDEN]);
    }

    while (g < ngroups) {
        const int gn = g + nwaves;
        if (gn < ngroups) {
            const float* base = ent + (size_t)gn * GRP_FLOATS;
            #pragma unroll
            for (int rr = 0; rr < ROWS_PER_GRP; ++rr)
                dma_row_16(base + rr * HIDDEN + lane * 4,
                           &lds[wslot][p ^ 1][rr * HIDDEN]);
            __builtin_amdgcn_s_waitcnt(WAITCNT_VM4);  // cur buf + old store done
        } else {
            __builtin_amdgcn_s_waitcnt(WAITCNT_VM0);
        }

        const float* buf = &lds[wslot][p][0];
        float res = 0.0f;
        const int q = (lane >> 3) & 3;
        #pragma unroll
        for (int j = 0; j < 2; ++j) {
            const float4 tA = *(const float4*)(buf + (2 * j + r_) * HIDDEN + c * 4);
            const float4 tB = *(const float4*)(buf + (2 * j + r_) * HIDDEN + 128 + c * 4);
            float acc[BATCH];
            #pragma unroll
            for (int b = 0; b < BATCH; ++b) {
                acc[b] = fabsf(hrA[b].x - tA.x) + fabsf(hrA[b].y - tA.y)
                       + fabsf(hrA[b].z - tA.z) + fabsf(hrA[b].w - tA.w)
                       + fabsf(hrB[b].x - tB.x) + fabsf(hrB[b].y - tB.y)
                       + fabsf(hrB[b].z - tB.z) + fabsf(hrB[b].w - tB.w);
            }
            // fold batch bits into lane bits 0..2
            float v[4];
            {
                const bool pb = lane & 1;
                #pragma unroll
                for (int k = 0; k < 4; ++k) {
                    const float keep = pb ? acc[2 * k + 1] : acc[2 * k];
                    const float give = pb ? acc[2 * k]     : acc[2 * k + 1];
                    v[k] = keep + __shfl_xor(give, 1, 64);
                }
            }
            float w2[2];
            {
                const bool pb = (lane >> 1) & 1;
                #pragma unroll
                for (int k = 0; k < 2; ++k) {
                    const float keep = pb ? v[2 * k + 1] : v[2 * k];
                    const float give = pb ? v[2 * k]     : v[2 * k + 1];
                    w2[k] = keep + __shfl_xor(give, 2, 64);
                }
            }
            float s;
            {
                const bool pb = (lane >> 2) & 1;
                const float keep = pb ? w2[1] : w2[0];
                const float give = pb ? w2[0] : w2[1];
                s = keep + __shfl_xor(give, 4, 64);
            }
            s += __shfl_xor(s, 8, 64);
            s += __shfl_xor(s, 16, 64);
            if (q == j) res = GAMMA_F - s;
        }
        // lane -> row = 2q + r_, batch = lane&7 ; 32 lanes, 2x64B contiguous
        if (q < 2)
            dist[(size_t)g * (ROWS_PER_GRP * BATCH) + q * 16 + r_ * 8 + (lane & 7)] = res;

        p ^= 1;
        g = gn;
    }

    // tail rows (none at nent=100000)
    if (wave_gid == 0) {
        for (int e = ngroups * ROWS_PER_GRP; e < nent; ++e) {
            const float* rowb = ent + (size_t)e * HIDDEN;
            const float4 uA = *(const float4*)(rowb + c * 4);
            const float4 uB = *(const float4*)(rowb + 128 + c * 4);
            float acc[BATCH];
            #pragma unroll
            for (int b = 0; b < BATCH; ++b) {
                acc[b] = fabsf(hrA[b].x - uA.x) + fabsf(hrA[b].y - uA.y)
                       + fabsf(hrA[b].z - uA.z) + fabsf(hrA[b].w - uA.w)
                       + fabsf(hrB[b].x - uB.x) + fabsf(hrB[b].y - uB.y)
                       + fabsf(hrB[b].z - uB.z) + fabsf(hrB[b].w - uB.w);
            }
            float v[4];
            {
                const bool pb = lane & 1;
                #pragma unroll
                for (int k = 0; k < 4; ++k) {
                    const float keep = pb ? acc[2 * k + 1] : acc[2 * k];
                    const float give = pb ? acc[2 * k]     : acc[2 * k + 1];
                    v[k] = keep + __shfl_xor(give, 1, 64);
                }
            }
            float w2[2];
            {
                const bool pb = (lane >> 1) & 1;
                #pragma unroll
                for (int k = 0; k < 2; ++k) {
                    const float keep = pb ? v[2 * k + 1] : v[2 * k];
                    const float give = pb ? v[2 * k]     : v[2 * k + 1];
                    w2[k] = keep + __shfl_xor(give, 2, 64);
                }
            }
            float s;
            {
                const bool pb = (lane >> 2) & 1;
                const float keep = pb ? w2[1] : w2[0];
                const float give = pb ? w2[0] : w2[1];
                s = keep + __shfl_xor(give, 4, 64);
            }
            s += __shfl_xor(s, 8, 64);
            s += __shfl_xor(s, 16, 64);
            if (lane < BATCH) dist[(size_t)e * BATCH + lane] = GAMMA_F - s;
        }
    }
}

// ---------------------------------------------------------------------------
// Kernel B: out[b,n] = dist[neg[b,n]*8 + b]. dist (3.2MB) is L2-resident.
// ---------------------------------------------------------------------------
__global__ __launch_bounds__(256) void kge_gather_kernel(
    const int*  __restrict__ neg,
    const float* __restrict__ dist,
    float* __restrict__ out,
    int nneg)
{
    const int b = blockIdx.y;
    const int n = (blockIdx.x * 256 + threadIdx.x) * 2;
    if (n + 1 < nneg) {
        const int2 idx = *(const int2*)(neg + (size_t)b * nneg + n);
        float2 r;
        r.x = dist[(size_t)idx.x * BATCH + b];
        r.y = dist[(size_t)idx.y * BATCH + b];
        *(float2*)(out + (size_t)b * nneg + n) = r;
    } else if (n < nneg) {
        out[(size_t)b * nneg + n] =
            dist[(size_t)neg[(size_t)b * nneg + n] * BATCH + b];
    }
}

extern "C" void kernel_launch(void* const* d_in, const int* in_sizes, int n_in,
                              void* d_out, int out_size, void* d_ws, size_t ws_size,
                              hipStream_t stream) {
    const float* ent = (const float*)d_in[0];   // [100000, 256] f32
    const float* rel = (const float*)d_in[1];   // [500, 256]    f32
    const int*   pos = (const int*)d_in[2];     // [8, 3]        int32
    const int*   neg = (const int*)d_in[3];     // [8, 100000]   int32
    float* out = (float*)d_out;                 // [8, 100000]   f32

    const int nent = in_sizes[0] / HIDDEN;      // 100000
    const int nneg = in_sizes[3] / BATCH;       // 100000
    float* dist = (float*)d_ws;                 // 3.2 MB (ws is larger)

    const int ngroups = nent / ROWS_PER_GRP;    // 25000
    const int nblocks = 1024;                   // 4096 waves, 4 blocks/CU
    const int nwaves = nblocks * 4;
    kge_dist_kernel<<<nblocks, 256, 0, stream>>>(ent, rel, pos, dist,
                                                 ngroups, nent, nwaves);

    const int npairs = (nneg + 1) / 2;
    dim3 gridB((npairs + 255) / 256, BATCH);
    kge_gather_kernel<<<gridB, 256, 0, stream>>>(neg, dist, out, nneg);
}

// Round 8
// 164.792 us; speedup vs baseline: 1.0092x; 1.0092x over previous
//
#include <hip/hip_runtime.h>

#define HIDDEN 256
#define GAMMA_F 12.0f
#define BATCH 8
#define ROWS_PER_GRP 4
#define GRP_FLOATS (ROWS_PER_GRP * HIDDEN)   // 1024 floats = 4 KB

// ---------------------------------------------------------------------------
// Kernel A: stream the entity table once. Persistent waves, 4 rows/group,
// REGISTER software pipeline: prefetch group g+nwaves into nxt[] at loop
// top, compute group g from cur[] (loaded one backedge ago), rotate.
// The loop-carried dependence forces the compiler to keep nxt[] live across
// the backedge -> 4 KB/wave permanently in flight (r4's flat staging was
// sunk to just-before-use: VGPR_Count=56 proved ~1 load in flight).
// Lane layout (r6, verified absmax 2.0): r_ = lane>>5 (row in pair),
// c = lane&31 (16B dim chunk). One load inst = 1 KB unique (two rows' halves).
// Per group: 2 independent 5-level pair-trees (9 swizzles each); lane l ends
// holding (rowpair r_, batch l&7) replicated over bits 3,4; latch copy q==j,
// half-wave 2x64B contiguous store.
// ---------------------------------------------------------------------------
__global__ __launch_bounds__(256, 4) void kge_dist_kernel(
    const float* __restrict__ ent,
    const float* __restrict__ rel,
    const int*  __restrict__ pos,
    float* __restrict__ dist,   // [nent, 8]
    int ngroups, int nent, int nwaves)
{
    const int lane = threadIdx.x & 63;
    const int r_ = lane >> 5;
    const int c = lane & 31;
    const int wave_gid = (blockIdx.x * 256 + threadIdx.x) >> 6;

    // hr[b] = head_b + rel_b at this lane's 8 dims (64 VGPRs, loaded once)
    float4 hrA[BATCH], hrB[BATCH];
    #pragma unroll
    for (int b = 0; b < BATCH; ++b) {
        const int hidx = pos[b * 3 + 0];
        const int ridx = pos[b * 3 + 1];
        const float* hrow = ent + (size_t)hidx * HIDDEN;
        const float* rrow = rel + (size_t)ridx * HIDDEN;
        float4 h = *(const float4*)(hrow + c * 4);
        float4 q4 = *(const float4*)(rrow + c * 4);
        hrA[b] = make_float4(h.x + q4.x, h.y + q4.y, h.z + q4.z, h.w + q4.w);
        h = *(const float4*)(hrow + 128 + c * 4);
        q4 = *(const float4*)(rrow + 128 + c * 4);
        hrB[b] = make_float4(h.x + q4.x, h.y + q4.y, h.z + q4.z, h.w + q4.w);
    }

    const int q = (lane >> 3) & 3;
    const int myrow_off = r_ * HIDDEN + c * 4;   // lane's slice within a pair

    int g = wave_gid;
    float4 curA[2], curB[2], nxtA[2], nxtB[2];

    if (g < ngroups) {
        const float* base = ent + (size_t)g * GRP_FLOATS;
        #pragma unroll
        for (int j = 0; j < 2; ++j) {
            curA[j] = *(const float4*)(base + 2 * j * HIDDEN + myrow_off);
            curB[j] = *(const float4*)(base + 2 * j * HIDDEN + myrow_off + 128);
        }
    }

    while (g < ngroups) {
        const int gn = g + nwaves;
        // prefetch next group (issued before any use of cur)
        if (gn < ngroups) {
            const float* base = ent + (size_t)gn * GRP_FLOATS;
            #pragma unroll
            for (int j = 0; j < 2; ++j) {
                nxtA[j] = *(const float4*)(base + 2 * j * HIDDEN + myrow_off);
                nxtB[j] = *(const float4*)(base + 2 * j * HIDDEN + myrow_off + 128);
            }
        }

        // compute current group from registers loaded one backedge ago
        float res = 0.0f;
        #pragma unroll
        for (int j = 0; j < 2; ++j) {
            const float4 tA = curA[j];
            const float4 tB = curB[j];
            float acc[BATCH];
            #pragma unroll
            for (int b = 0; b < BATCH; ++b) {
                acc[b] = fabsf(hrA[b].x - tA.x) + fabsf(hrA[b].y - tA.y)
                       + fabsf(hrA[b].z - tA.z) + fabsf(hrA[b].w - tA.w)
                       + fabsf(hrB[b].x - tB.x) + fabsf(hrB[b].y - tB.y)
                       + fabsf(hrB[b].z - tB.z) + fabsf(hrB[b].w - tB.w);
            }
            // fold batch bits into lane bits 0..2
            float v[4];
            {
                const bool pb = lane & 1;
                #pragma unroll
                for (int k = 0; k < 4; ++k) {
                    const float keep = pb ? acc[2 * k + 1] : acc[2 * k];
                    const float give = pb ? acc[2 * k]     : acc[2 * k + 1];
                    v[k] = keep + __shfl_xor(give, 1, 64);
                }
            }
            float w2[2];
            {
                const bool pb = (lane >> 1) & 1;
                #pragma unroll
                for (int k = 0; k < 2; ++k) {
                    const float keep = pb ? v[2 * k + 1] : v[2 * k];
                    const float give = pb ? v[2 * k]     : v[2 * k + 1];
                    w2[k] = keep + __shfl_xor(give, 2, 64);
                }
            }
            float s;
            {
                const bool pb = (lane >> 2) & 1;
                const float keep = pb ? w2[1] : w2[0];
                const float give = pb ? w2[0] : w2[1];
                s = keep + __shfl_xor(give, 4, 64);
            }
            s += __shfl_xor(s, 8, 64);
            s += __shfl_xor(s, 16, 64);
            if (q == j) res = GAMMA_F - s;
        }
        // lane -> row = 2q + r_, batch = lane&7 ; 32 lanes, 2x64B contiguous
        if (q < 2)
            dist[(size_t)g * (ROWS_PER_GRP * BATCH) + q * 16 + r_ * 8 + (lane & 7)] = res;

        // rotate pipeline registers
        #pragma unroll
        for (int j = 0; j < 2; ++j) { curA[j] = nxtA[j]; curB[j] = nxtB[j]; }
        g = gn;
    }

    // tail rows (none at nent=100000)
    if (wave_gid == 0) {
        for (int e = ngroups * ROWS_PER_GRP; e < nent; ++e) {
            const float* rowb = ent + (size_t)e * HIDDEN;
            const float4 uA = *(const float4*)(rowb + c * 4);
            const float4 uB = *(const float4*)(rowb + 128 + c * 4);
            float acc[BATCH];
            #pragma unroll
            for (int b = 0; b < BATCH; ++b) {
                acc[b] = fabsf(hrA[b].x - uA.x) + fabsf(hrA[b].y - uA.y)
                       + fabsf(hrA[b].z - uA.z) + fabsf(hrA[b].w - uA.w)
                       + fabsf(hrB[b].x - uB.x) + fabsf(hrB[b].y - uB.y)
                       + fabsf(hrB[b].z - uB.z) + fabsf(hrB[b].w - uB.w);
            }
            float v[4];
            {
                const bool pb = lane & 1;
                #pragma unroll
                for (int k = 0; k < 4; ++k) {
                    const float keep = pb ? acc[2 * k + 1] : acc[2 * k];
                    const float give = pb ? acc[2 * k]     : acc[2 * k + 1];
                    v[k] = keep + __shfl_xor(give, 1, 64);
                }
            }
            float w2[2];
            {
                const bool pb = (lane >> 1) & 1;
                #pragma unroll
                for (int k = 0; k < 2; ++k) {
                    const float keep = pb ? v[2 * k + 1] : v[2 * k];
                    const float give = pb ? v[2 * k]     : v[2 * k + 1];
                    w2[k] = keep + __shfl_xor(give, 2, 64);
                }
            }
            float s;
            {
                const bool pb = (lane >> 2) & 1;
                const float keep = pb ? w2[1] : w2[0];
                const float give = pb ? w2[0] : w2[1];
                s = keep + __shfl_xor(give, 4, 64);
            }
            s += __shfl_xor(s, 8, 64);
            s += __shfl_xor(s, 16, 64);
            if (lane < BATCH) dist[(size_t)e * BATCH + lane] = GAMMA_F - s;
        }
    }
}

// ---------------------------------------------------------------------------
// Kernel B: out[b,n] = dist[neg[b,n]*8 + b]. dist (3.2MB) is L2-resident.
// ---------------------------------------------------------------------------
__global__ __launch_bounds__(256) void kge_gather_kernel(
    const int*  __restrict__ neg,
    const float* __restrict__ dist,
    float* __restrict__ out,
    int nneg)
{
    const int b = blockIdx.y;
    const int n = (blockIdx.x * 256 + threadIdx.x) * 2;
    if (n + 1 < nneg) {
        const int2 idx = *(const int2*)(neg + (size_t)b * nneg + n);
        float2 r;
        r.x = dist[(size_t)idx.x * BATCH + b];
        r.y = dist[(size_t)idx.y * BATCH + b];
        *(float2*)(out + (size_t)b * nneg + n) = r;
    } else if (n < nneg) {
        out[(size_t)b * nneg + n] =
            dist[(size_t)neg[(size_t)b * nneg + n] * BATCH + b];
    }
}

extern "C" void kernel_launch(void* const* d_in, const int* in_sizes, int n_in,
                              void* d_out, int out_size, void* d_ws, size_t ws_size,
                              hipStream_t stream) {
    const float* ent = (const float*)d_in[0];   // [100000, 256] f32
    const float* rel = (const float*)d_in[1];   // [500, 256]    f32
    const int*   pos = (const int*)d_in[2];     // [8, 3]        int32
    const int*   neg = (const int*)d_in[3];     // [8, 100000]   int32
    float* out = (float*)d_out;                 // [8, 100000]   f32

    const int nent = in_sizes[0] / HIDDEN;      // 100000
    const int nneg = in_sizes[3] / BATCH;       // 100000
    float* dist = (float*)d_ws;                 // 3.2 MB (ws is larger)

    const int ngroups = nent / ROWS_PER_GRP;    // 25000
    const int nblocks = 1024;                   // 4 blocks/CU, 4 waves/SIMD
    const int nwaves = nblocks * 4;
    kge_dist_kernel<<<nblocks, 256, 0, stream>>>(ent, rel, pos, dist,
                                                 ngroups, nent, nwaves);

    const int npairs = (nneg + 1) / 2;
    dim3 gridB((npairs + 255) / 256, BATCH);
    kge_gather_kernel<<<gridB, 256, 0, stream>>>(neg, dist, out, nneg);
}

// Round 9
// 163.643 us; speedup vs baseline: 1.0163x; 1.0070x over previous
//
#include <hip/hip_runtime.h>

#define HIDDEN 256
#define GAMMA_F 12.0f
#define BATCH 8

// ---------------------------------------------------------------------------
// Kernel A: stream the entity table once — PURE TLP variant.
// Four rounds of ILP engineering (multi-row staging, LDS-DMA double-buffer,
// loop-carried register pipeline) were all neutral at ~46us: the compiler
// keeps ~1 load in flight per wave no matter what, and at 1024 blocks only
// 16 of 32 waves/CU were resident (r4: Occupancy 34%, VGPR 56). So: go
// minimal-VGPR (hr=32 + t=4 + acc=8 + addr ~ 50 regs), cap at 64 via
// __launch_bounds__(256,8), and launch 2048 blocks -> 32 waves/CU. Aggregate
// in-flight bytes double (~26KB/CU -> ~6.7MB device) -> HBM-bound.
// Lane layout: lane covers dims [4*lane, 4*lane+4) — one float4 load inst
// moves one full 1KB row of unique contiguous data.
// Reduction (verified r4/r5): merge-tree — offsets 1,2,4 fold the 3 batch
// bits into lane bits 0..2, offsets 8,16,32 butterfly; lane l ends with the
// complete sum for batch l&7; lanes 0..7 store 32B contiguous.
// ---------------------------------------------------------------------------
__global__ __launch_bounds__(256, 8) void kge_dist_kernel(
    const float* __restrict__ ent,
    const float* __restrict__ rel,
    const int*  __restrict__ pos,
    float* __restrict__ dist,   // [nent, 8]
    int nent, int nwaves)
{
    const int lane = threadIdx.x & 63;
    const int wave_gid = (blockIdx.x * 256 + threadIdx.x) >> 6;

    // hr[b] = head_b + rel_b at dims [4*lane, 4*lane+4) — 32 VGPRs, once
    float4 hr[BATCH];
    #pragma unroll
    for (int b = 0; b < BATCH; ++b) {
        const int hidx = pos[b * 3 + 0];
        const int ridx = pos[b * 3 + 1];
        const float4 h4 = *(const float4*)(ent + (size_t)hidx * HIDDEN + lane * 4);
        const float4 r4 = *(const float4*)(rel + (size_t)ridx * HIDDEN + lane * 4);
        hr[b] = make_float4(h4.x + r4.x, h4.y + r4.y, h4.z + r4.z, h4.w + r4.w);
    }

    for (int e = wave_gid; e < nent; e += nwaves) {
        const float4 t4 = *(const float4*)(ent + (size_t)e * HIDDEN + lane * 4);

        float acc[BATCH];
        #pragma unroll
        for (int b = 0; b < BATCH; ++b) {
            acc[b] = fabsf(hr[b].x - t4.x) + fabsf(hr[b].y - t4.y)
                   + fabsf(hr[b].z - t4.z) + fabsf(hr[b].w - t4.w);
        }

        // fold batch bits into lane bits 0..2
        float v[4];
        {
            const bool p = lane & 1;
            #pragma unroll
            for (int k = 0; k < 4; ++k) {
                const float keep = p ? acc[2 * k + 1] : acc[2 * k];
                const float give = p ? acc[2 * k]     : acc[2 * k + 1];
                v[k] = keep + __shfl_xor(give, 1, 64);
            }
        }
        float w2[2];
        {
            const bool p = (lane >> 1) & 1;
            #pragma unroll
            for (int k = 0; k < 2; ++k) {
                const float keep = p ? v[2 * k + 1] : v[2 * k];
                const float give = p ? v[2 * k]     : v[2 * k + 1];
                w2[k] = keep + __shfl_xor(give, 2, 64);
            }
        }
        float s;
        {
            const bool p = (lane >> 2) & 1;
            const float keep = p ? w2[1] : w2[0];
            const float give = p ? w2[0] : w2[1];
            s = keep + __shfl_xor(give, 4, 64);
        }
        s += __shfl_xor(s, 8, 64);
        s += __shfl_xor(s, 16, 64);
        s += __shfl_xor(s, 32, 64);

        if (lane < BATCH)
            dist[(size_t)e * BATCH + lane] = GAMMA_F - s;
    }
}

// ---------------------------------------------------------------------------
// Kernel B: out[b,n] = dist[neg[b,n]*8 + b]. dist (3.2MB) is L2-resident.
// 2 outputs/thread: int2 index load, 2 independent gathers, float2 store.
// ---------------------------------------------------------------------------
__global__ __launch_bounds__(256) void kge_gather_kernel(
    const int*  __restrict__ neg,
    const float* __restrict__ dist,
    float* __restrict__ out,
    int nneg)
{
    const int b = blockIdx.y;
    const int n = (blockIdx.x * 256 + threadIdx.x) * 2;
    if (n + 1 < nneg) {
        const int2 idx = *(const int2*)(neg + (size_t)b * nneg + n);
        float2 r;
        r.x = dist[(size_t)idx.x * BATCH + b];
        r.y = dist[(size_t)idx.y * BATCH + b];
        *(float2*)(out + (size_t)b * nneg + n) = r;
    } else if (n < nneg) {
        out[(size_t)b * nneg + n] =
            dist[(size_t)neg[(size_t)b * nneg + n] * BATCH + b];
    }
}

extern "C" void kernel_launch(void* const* d_in, const int* in_sizes, int n_in,
                              void* d_out, int out_size, void* d_ws, size_t ws_size,
                              hipStream_t stream) {
    const float* ent = (const float*)d_in[0];   // [100000, 256] f32
    const float* rel = (const float*)d_in[1];   // [500, 256]    f32
    const int*   pos = (const int*)d_in[2];     // [8, 3]        int32
    const int*   neg = (const int*)d_in[3];     // [8, 100000]   int32
    float* out = (float*)d_out;                 // [8, 100000]   f32

    const int nent = in_sizes[0] / HIDDEN;      // 100000
    const int nneg = in_sizes[3] / BATCH;       // 100000
    float* dist = (float*)d_ws;                 // 3.2 MB (ws is larger)

    // 2048 blocks = 8 blocks/CU = 32 waves/CU (needs VGPR<=64 -> bounds(256,8))
    const int nblocks = 2048;
    const int nwaves = nblocks * 4;
    kge_dist_kernel<<<nblocks, 256, 0, stream>>>(ent, rel, pos, dist,
                                                 nent, nwaves);

    const int npairs = (nneg + 1) / 2;
    dim3 gridB((npairs + 255) / 256, BATCH);
    kge_gather_kernel<<<gridB, 256, 0, stream>>>(neg, dist, out, nneg);
}